// Round 14
// baseline (156.817 us; speedup 1.0000x reference)
//
#include <hip/hip_runtime.h>
#include <hip/hip_bf16.h>

// ---------------------------------------------------------------------------
// BidirectionalCrossAttention on MI355X.
// R14: revert R13's cross-block combine (device-scope __threadfence inside
// the hot kernel invalidates XCD L2 on CDNA4 -> 2x latency, measured 88us).
// Occupancy instead via 6-wave (384-thr) blocks: grid (8,64) = 512 blocks =
// 2 blocks/CU x 6 waves = 3 waves/SIMD, __launch_bounds__(384,3) caps VGPR
// at 170 (kernel uses ~116 -> no spill). Waves split i as {22,22,22,22,20,20}
// tiles (even counts keep the 2-deep prefetch pair-loop). 3-round LDS reduce.
// All other kernels identical to R12 (best: 92.1us).
// ---------------------------------------------------------------------------

using bf16x8 = __attribute__((ext_vector_type(8))) short;
using f32x4  = __attribute__((ext_vector_type(4))) float;
using f32x16 = __attribute__((ext_vector_type(16))) float;
typedef unsigned int uint2v __attribute__((ext_vector_type(2)));

#define MFMA16(a, b, c) __builtin_amdgcn_mfma_f32_16x16x32_bf16((a), (b), (c), 0, 0, 0)
#define MFMA32(a, b, c) __builtin_amdgcn_mfma_f32_32x32x16_bf16((a), (b), (c), 0, 0, 0)

constexpr int B_ = 4, C_ = 64, S_ = 4096;
constexpr float kQS = 0.18033688f;  // 0.125 * log2(e), folded into wq/bq

// workspace byte offsets
constexpr size_t OFF_XT   = 0;                        // 2*B*S*C ushort = 4 MiB
constexpr size_t OFF_WB   = 4u * 1024 * 1024;         // 7*4096 ushort
constexpr size_t OFF_FW1R = OFF_WB + 64 * 1024;       // 64*1152 ushort
constexpr size_t OFF_QT   = OFF_FW1R + 160 * 1024;    // Qf fragment-major
constexpr size_t OFF_KT   = OFF_QT + 4u * 1024 * 1024;   // Kf
constexpr size_t OFF_V    = OFF_KT + 4u * 1024 * 1024;   // Vf
constexpr size_t OFF_COMB = OFF_V + 4u * 1024 * 1024; // B*S*128 ushort
constexpr size_t OFF_Y    = OFF_COMB + 4u * 1024 * 1024; // B*S*64 f32
constexpr size_t OFF_PART = OFF_Y + 4u * 1024 * 1024; // 2*64*1024 f32 = 512KB
constexpr size_t OFF_BNA  = OFF_PART + 512 * 1024;
constexpr size_t OFF_BNB  = OFF_BNA + 1024;

__device__ __forceinline__ unsigned short f2bf(float f) {
  unsigned int u = __float_as_uint(f);
  unsigned int r = (u + 0x7fffu + ((u >> 16) & 1u)) >> 16;
  return (unsigned short)r;
}
__device__ __forceinline__ unsigned int cvt_pk_bf16(float lo, float hi) {
  unsigned int r;
  asm("v_cvt_pk_bf16_f32 %0, %1, %2" : "=v"(r) : "v"(lo), "v"(hi));
  return r;
}
__device__ __forceinline__ float fast_exp2(float x) {
#if __has_builtin(__builtin_amdgcn_exp2f)
  return __builtin_amdgcn_exp2f(x);
#else
  return exp2f(x);
#endif
}
__device__ __forceinline__ void plswap(unsigned int& a, unsigned int& b) {
  uint2v r = __builtin_amdgcn_permlane32_swap(a, b, false, false);
  a = r[0];
  b = r[1];
}

// exp2 of 16 S-values, accumulate denominator, build 2 PV B-fragments
// (i-halves) via cvt_pk + permlane32_swap. Lane layout: col j = lane&31,
// rows i = (reg&3) + 8*(reg>>2) + 4*(lane>>5).  [verified R4-R12]
__device__ __forceinline__ void build_pv_frags(const f32x16 s, float& lsum,
                                               bf16x8* out) {
  float p[16];
#pragma unroll
  for (int r = 0; r < 16; ++r) p[r] = fast_exp2(s[r]);
  lsum += (((p[0] + p[1]) + (p[2] + p[3])) + ((p[4] + p[5]) + (p[6] + p[7]))) +
          (((p[8] + p[9]) + (p[10] + p[11])) + ((p[12] + p[13]) + (p[14] + p[15])));
#pragma unroll
  for (int h = 0; h < 2; ++h) {
    unsigned int X  = cvt_pk_bf16(p[8 * h + 0], p[8 * h + 1]);
    unsigned int X2 = cvt_pk_bf16(p[8 * h + 2], p[8 * h + 3]);
    unsigned int Y  = cvt_pk_bf16(p[8 * h + 4], p[8 * h + 5]);
    unsigned int Y2 = cvt_pk_bf16(p[8 * h + 6], p[8 * h + 7]);
    plswap(X, Y);
    plswap(X2, Y2);
    union { unsigned int u[4]; bf16x8 v; } bb;
    bb.u[0] = X; bb.u[1] = X2; bb.u[2] = Y; bb.u[3] = Y2;
    out[h] = bb.v;
  }
}

// --------------------------- K0: weight prep + x transpose -----------------
__global__ void k_prep(const float* wq1, const float* wk1, const float* wv1,
                       const float* wq2, const float* wk2, const float* wv2,
                       const float* fw2, const float* fw1,
                       const float* xs2, const float* xdem,
                       unsigned short* wb, unsigned short* fw1r,
                       unsigned short* xT) {
  __shared__ float lds[64][65];
  if (blockIdx.x < 400) {
    int g = blockIdx.x * 256 + threadIdx.x;
    if (g < 7 * 4096) {
      int m = g >> 12, idx = g & 4095;
      const float* src[7] = {wq1, wk1, wv1, wq2, wk2, wv2, fw2};
      float sc = (m == 0 || m == 3) ? kQS : 1.0f;  // fold softmax scale into Q
      wb[g] = f2bf(src[m][idx] * sc);
    } else {
      int t = g - 7 * 4096;
      if (t < 64 * 1152) {
        int o = t / 1152, kk = t % 1152;
        int dydx = kk >> 7, ci = kk & 127;
        fw1r[t] = f2bf(fw1[o * 1152 + ci * 9 + dydx]);
      }
    }
    return;
  }
  int bid = blockIdx.x - 400;
  int pt = bid & 63, b = (bid >> 6) & 3, tz = bid >> 8;
  int tid = threadIdx.x;
  const float* src = (tz == 0) ? xs2 : xdem;
  int p0 = pt * 64;
#pragma unroll
  for (int k = 0; k < 16; ++k) {
    int idx = k * 256 + tid;
    int c = idx >> 6, pp = idx & 63;
    lds[c][pp] = src[((size_t)(b * 64 + c) << 12) + p0 + pp];
  }
  __syncthreads();
  unsigned short* dst = xT + (size_t)tz * (B_ * S_ * C_);
#pragma unroll
  for (int k = 0; k < 4; ++k) {
    int p = (tid >> 4) + k * 16;
    int c0 = (tid & 15) * 4;
    ushort4 v;
    v.x = f2bf(lds[c0 + 0][p]);
    v.y = f2bf(lds[c0 + 1][p]);
    v.z = f2bf(lds[c0 + 2][p]);
    v.w = f2bf(lds[c0 + 3][p]);
    *(ushort4*)&dst[((size_t)((b << 12) + p0 + p)) * 64 + c0] = v;
  }
}

// --------------------------- K2: projections (fragment-major outputs) ------
// Qf/Kf: [cchunk 4][p 4096][c 16] ushort; Vf: [ichunk 256][c 64][i 16].
__global__ __launch_bounds__(256) void k_proj(
    const unsigned short* xT, const unsigned short* wb,
    const float* bq1, const float* bk1, const float* bv1,
    const float* bq2, const float* bk2, const float* bv2,
    unsigned short* Qf, unsigned short* Kf, unsigned short* Vf) {
  int pc = blockIdx.x, b = blockIdx.y, dir = blockIdx.z;
  int lane = threadIdx.x & 63, wid = threadIdx.x >> 6;
  int l4 = lane & 15, g4 = lane >> 4;
  const unsigned short* xq =
      xT + ((size_t)(dir * B_ + b)) * (size_t)(S_ * C_);        // query src
  const unsigned short* xkv =
      xT + ((size_t)((1 - dir) * B_ + b)) * (size_t)(S_ * C_);  // key/val src
  size_t dbOff = ((size_t)dir * B_ + b) * (size_t)(S_ * C_);
  const float* bq = dir ? bq2 : bq1;
  const float* bk = dir ? bk2 : bk1;
  const float* bv = dir ? bv2 : bv1;
  int pbase = pc * 64 + wid * 16;

  bf16x8 aq[2], akv[2];
#pragma unroll
  for (int kc = 0; kc < 2; ++kc) {
    aq[kc] = *(const bf16x8*)&xq[(size_t)(pbase + l4) * 64 + kc * 32 + g4 * 8];
    akv[kc] = *(const bf16x8*)&xkv[(size_t)(pbase + l4) * 64 + kc * 32 + g4 * 8];
  }

  // Q and K -> fragment-major [nt][p][l4]
#pragma unroll
  for (int prod = 0; prod < 2; ++prod) {
    const unsigned short* wm = wb + (dir * 3 + prod) * 4096;
    unsigned short* dst = (prod == 0 ? Qf : Kf) + dbOff;
    const float* bp = (prod == 0) ? bq : bk;
    float bscale = (prod == 0) ? kQS : 1.0f;
    const bf16x8* af = (prod == 0) ? aq : akv;
#pragma unroll
    for (int nt = 0; nt < 4; ++nt) {
      bf16x8 wf0 = *(const bf16x8*)&wm[(nt * 16 + l4) * 64 + g4 * 8];
      bf16x8 wf1 = *(const bf16x8*)&wm[(nt * 16 + l4) * 64 + 32 + g4 * 8];
      f32x4 acc = {0.f, 0.f, 0.f, 0.f};
      acc = MFMA16(af[0], wf0, acc);
      acc = MFMA16(af[1], wf1, acc);
      float bias_c = bp[nt * 16 + l4] * bscale;
#pragma unroll
      for (int r = 0; r < 4; ++r)
        dst[(size_t)nt * 65536 + (size_t)(pbase + g4 * 4 + r) * 16 + l4] =
            f2bf(acc[r] + bias_c);
    }
  }
  // V -> fragment-major [p>>4][c][p&15]
  {
    const unsigned short* wm = wb + (dir * 3 + 2) * 4096;
    unsigned short* dst = Vf + dbOff;
#pragma unroll
    for (int mt = 0; mt < 4; ++mt) {
      bf16x8 wf0 = *(const bf16x8*)&wm[(mt * 16 + l4) * 64 + g4 * 8];
      bf16x8 wf1 = *(const bf16x8*)&wm[(mt * 16 + l4) * 64 + 32 + g4 * 8];
      f32x4 acc = {0.f, 0.f, 0.f, 0.f};
      acc = MFMA16(wf0, akv[0], acc);
      acc = MFMA16(wf1, akv[1], acc);
#pragma unroll
      for (int r = 0; r < 4; ++r) {
        int c = mt * 16 + g4 * 4 + r;
        dst[(size_t)(pbase >> 4) * 1024 + c * 16 + l4] = f2bf(acc[r] + bv[c]);
      }
    }
  }
}

// --------------------------- K5: fused flash attention (LDS-free, j64) -----
// Grid (8 bd, 64 jb): linear%8 = bd -> XCD-local Qf/Kf/Vf (1.5MB < 4MB L2).
// 384 thr = 6 waves; wave w owns {22,22,22,22,20,20} 32-i tiles, j-tile 64.
// 2-deep register prefetch. 512 blocks = 2/CU x 6 waves = 3 waves/SIMD.
// LDS: 3 reduce slots x 16KB + Lp; 3-round in-block reduce (no fences!).
constexpr int TST = 72;

__global__ __launch_bounds__(384, 3) void k_attn(
    const unsigned short* Qf, const unsigned short* Kf, const unsigned short* Vf,
    const float* xs2, const float* xdem,
    const float* lnw_s2, const float* lnb_s2,
    const float* lnw_dem, const float* lnb_dem,
    unsigned short* comb) {
  __shared__ __align__(16) char smem[52224];  // 3 x 16384 slots + Lp 3072
  const f32x16 kZero16 = {0.f, 0.f, 0.f, 0.f, 0.f, 0.f, 0.f, 0.f,
                          0.f, 0.f, 0.f, 0.f, 0.f, 0.f, 0.f, 0.f};
  int bd = blockIdx.x, jb = blockIdx.y;
  int dir = bd >> 2, b = bd & 3;
  int lane = threadIdx.x & 63, wid = threadIdx.x >> 6;
  int l5 = lane & 31;
  int h = lane >> 5;
  int hi8 = h * 8, hi4 = h * 4;
  size_t dbOff = (size_t)bd * (size_t)(S_ * C_);
  const unsigned short* qp = Qf + dbOff;
  const unsigned short* kp = Kf + dbOff;
  const unsigned short* vp = Vf + dbOff;

  int jbase = jb * 64;
  // resident Q fragments for 2 j-groups (coalesced from fragment-major Qf)
  bf16x8 qf[2][4];
#pragma unroll
  for (int jg = 0; jg < 2; ++jg)
#pragma unroll
    for (int kc = 0; kc < 4; ++kc)
      qf[jg][kc] = *(const bf16x8*)&qp[(size_t)kc * 65536 +
                                       (size_t)(jbase + jg * 32 + l5) * 16 + hi8];

  f32x16 acc00 = kZero16, acc01 = kZero16, acc10 = kZero16, acc11 = kZero16;
  float lsum0 = 0.f, lsum1 = 0.f;
  // wave tile ranges: waves 0-3 -> 22 tiles, waves 4-5 -> 20 tiles (even)
  int cnt = (wid < 4) ? 22 : 20;
  int ibeg = ((wid < 4) ? wid * 22 : 88 + (wid - 4) * 20) * 32;

#define LOADT(AK, AV, I0)                                                    \
  {                                                                          \
    int i0_ = (I0);                                                          \
    _Pragma("unroll") for (int k_ = 0; k_ < 4; ++k_)                         \
        (AK)[k_] = *(const bf16x8*)&kp[(size_t)k_ * 65536 +                  \
                                       (size_t)(i0_ + l5) * 16 + hi8];       \
    int ic_ = i0_ >> 4;                                                      \
    (AV)[0] = *(const bf16x8*)&vp[(size_t)ic_ * 1024 + l5 * 16 + hi8];       \
    (AV)[1] = *(const bf16x8*)&vp[(size_t)(ic_ + 1) * 1024 + l5 * 16 + hi8]; \
    (AV)[2] = *(const bf16x8*)&vp[(size_t)ic_ * 1024 + (32 + l5) * 16 + hi8];\
    (AV)[3] = *(const bf16x8*)&vp[(size_t)(ic_ + 1) * 1024 + (32 + l5) * 16 + hi8];\
  }

#define TILE(AK, AV)                                                         \
  {                                                                          \
    f32x16 S0 = kZero16;                                                     \
    S0 = MFMA32((AK)[0], qf[0][0], S0);                                      \
    S0 = MFMA32((AK)[1], qf[0][1], S0);                                      \
    S0 = MFMA32((AK)[2], qf[0][2], S0);                                      \
    S0 = MFMA32((AK)[3], qf[0][3], S0);                                      \
    bf16x8 pb0[2];                                                           \
    build_pv_frags(S0, lsum0, pb0);                                          \
    f32x16 S1 = kZero16;                                                     \
    S1 = MFMA32((AK)[0], qf[1][0], S1);                                      \
    S1 = MFMA32((AK)[1], qf[1][1], S1);                                      \
    S1 = MFMA32((AK)[2], qf[1][2], S1);                                      \
    S1 = MFMA32((AK)[3], qf[1][3], S1);                                      \
    bf16x8 pb1[2];                                                           \
    build_pv_frags(S1, lsum1, pb1);                                          \
    acc00 = MFMA32((AV)[0], pb0[0], acc00);                                  \
    acc00 = MFMA32((AV)[1], pb0[1], acc00);                                  \
    acc01 = MFMA32((AV)[2], pb0[0], acc01);                                  \
    acc01 = MFMA32((AV)[3], pb0[1], acc01);                                  \
    acc10 = MFMA32((AV)[0], pb1[0], acc10);                                  \
    acc10 = MFMA32((AV)[1], pb1[1], acc10);                                  \
    acc11 = MFMA32((AV)[2], pb1[0], acc11);                                  \
    acc11 = MFMA32((AV)[3], pb1[1], acc11);                                  \
  }

  // 2-deep prefetch; reads past own range stay inside the workspace.
  bf16x8 akA[4], avA[4], akB[4], avB[4];
  LOADT(akA, avA, ibeg)
  for (int t = 0; t < cnt; t += 2) {
    LOADT(akB, avB, ibeg + (t + 1) * 32)
    TILE(akA, avA)
    LOADT(akA, avA, ibeg + (t + 2) * 32)
    TILE(akB, avB)
  }
#undef LOADT
#undef TILE

  // in-block reduce of the 6 waves' partials over 3 LDS slots (3 rounds)
  float* Lp = (float*)(smem + 49152);
  Lp[wid * 128 + lane] = lsum0;
  Lp[wid * 128 + 64 + lane] = lsum1;

#define STORE1(A_, CIDX, RG)                                              \
  {                                                                       \
    _Pragma("unroll") for (int q2 = 0; q2 < 4; ++q2) {                    \
      f32x4 tv = {(A_)[q2 * 4 + 0], (A_)[q2 * 4 + 1],                     \
                  (A_)[q2 * 4 + 2], (A_)[q2 * 4 + 3]};                    \
      *(f32x4*)&(RG)[((CIDX) * 4 + q2) * 256 + lane * 4] = tv;            \
    }                                                                     \
  }
#define ADD1(A_, CIDX, RR)                                                \
  {                                                                       \
    _Pragma("unroll") for (int q2 = 0; q2 < 4; ++q2) {                    \
      f32x4 tv = *(const f32x4*)&(RR)[((CIDX) * 4 + q2) * 256 + lane * 4];\
      _Pragma("unroll") for (int e = 0; e < 4; ++e) (A_)[q2 * 4 + e] += tv[e]; \
    }                                                                     \
  }
#define PUB(SLOT)                                                         \
  {                                                                       \
    float* rg_ = (float*)(smem + (size_t)(SLOT) * 16384);                 \
    STORE1(acc00, 0, rg_) STORE1(acc01, 1, rg_)                           \
    STORE1(acc10, 2, rg_) STORE1(acc11, 3, rg_)                           \
  }
#define ADDP(SLOT)                                                        \
  {                                                                       \
    const float* rr_ = (const float*)(smem + (size_t)(SLOT) * 16384);     \
    ADD1(acc00, 0, rr_) ADD1(acc01, 1, rr_)                               \
    ADD1(acc10, 2, rr_) ADD1(acc11, 3, rr_)                               \
  }

  if (wid >= 3) PUB(wid - 3)
  __syncthreads();
  if (wid < 3) ADDP(wid)
  __syncthreads();
  if (wid == 1 || wid == 2) PUB(wid - 1)
  __syncthreads();
  if (wid != 0) return;
  ADDP(0)
  ADDP(1)
#undef PUB
#undef ADDP
#undef STORE1
#undef ADD1

  // final wave: denominators, residual, LayerNorm, comb write for j64
  const float* xa = (dir == 0 ? xs2 : xdem) + (size_t)b * C_ * S_;
  const float* lw = (dir == 0) ? lnw_s2 : lnw_dem;
  const float* lbp = (dir == 0) ? lnb_s2 : lnb_dem;
  unsigned short* T = (unsigned short*)smem;  // slot region free now

#pragma unroll
  for (int jg = 0; jg < 2; ++jg) {
    float ls = 0.f;
#pragma unroll
    for (int w = 0; w < 6; ++w) ls += Lp[w * 128 + jg * 64 + lane];
    ls += __shfl_xor(ls, 32);
    float linv = 1.0f / ls;
    int jcol = jbase + jg * 32 + l5;

    float vals[32];
    float s1 = 0.f, s2 = 0.f;
#pragma unroll
    for (int ct = 0; ct < 2; ++ct)
#pragma unroll
      for (int reg = 0; reg < 16; ++reg) {
        int c = ct * 32 + (reg & 3) + 8 * (reg >> 2) + hi4;
        float a_ = (jg == 0) ? (ct == 0 ? acc00[reg] : acc01[reg])
                             : (ct == 0 ? acc10[reg] : acc11[reg]);
        float v = a_ * linv + xa[(size_t)c * S_ + jcol];
        vals[ct * 16 + reg] = v;
        s1 += v;
        s2 += v * v;
      }
    s1 += __shfl_xor(s1, 32);
    s2 += __shfl_xor(s2, 32);
    float mean = s1 * (1.0f / 64.0f);
    float var = s2 * (1.0f / 64.0f) - mean * mean;
    float rstd = rsqrtf(var + 1e-5f);

#pragma unroll
    for (int ct = 0; ct < 2; ++ct)
#pragma unroll
      for (int q2 = 0; q2 < 4; ++q2)
#pragma unroll
        for (int pp = 0; pp < 2; ++pp) {
          int r0 = q2 * 4 + pp * 2;
          int c0 = ct * 32 + 8 * q2 + hi4 + pp * 2;
          float x0 = (vals[ct * 16 + r0 + 0] - mean) * rstd * lw[c0 + 0] + lbp[c0 + 0];
          float x1 = (vals[ct * 16 + r0 + 1] - mean) * rstd * lw[c0 + 1] + lbp[c0 + 1];
          *(unsigned int*)&T[l5 * TST + c0] = cvt_pk_bf16(x0, x1);
        }
    int j_l = lane >> 1, cc = (lane & 1) * 32;
    unsigned short* cb =
        comb + ((size_t)b * S_ + jbase + jg * 32 + j_l) * 128 + dir * 64 + cc;
    const unsigned short* ts = &T[j_l * TST + cc];
#pragma unroll
    for (int q = 0; q < 4; ++q) {
      uint4 tq = *(const uint4*)&ts[q * 8];
      *(uint4*)&cb[q * 8] = tq;
    }
  }
}

// --------------------------- K6: 3x3 conv + fused BN partial sums ----------
// Grid (256 pc, 4 b), 128 thr = 2 waves; wave wid handles oc [wid*32,+32).
// Partials written channel-major: part[ch][blk], part2 at +65536 floats.
__global__ __launch_bounds__(128) void k_conv3(const unsigned short* comb,
                                               const unsigned short* fw1r,
                                               const float* fb1, float* y,
                                               float* part) {
  int pc = blockIdx.x, b = blockIdx.y;
  int lane = threadIdx.x & 63, wid = threadIdx.x >> 6;
  int l4 = lane & 15, g4 = lane >> 4;
  int p0 = pc * 16;
  int p_l = p0 + l4;
  int py0 = p_l >> 6, px0 = p_l & 63;
  f32x4 acc[2];
#pragma unroll
  for (int o = 0; o < 2; ++o) acc[o] = f32x4{0.f, 0.f, 0.f, 0.f};

#pragma unroll
  for (int kk9 = 0; kk9 < 9; ++kk9) {
    int py = py0 + (kk9 / 3) - 1;
    int px = px0 + (kk9 % 3) - 1;
    bool ok = (py >= 0) && (py < 64) && (px >= 0) && (px < 64);
    const unsigned short* base = comb + ((size_t)(b << 12) + py * 64 + px) * 128;
#pragma unroll
    for (int kc = 0; kc < 4; ++kc) {
      bf16x8 af = {0, 0, 0, 0, 0, 0, 0, 0};
      if (ok) af = *(const bf16x8*)&base[kc * 32 + g4 * 8];
#pragma unroll
      for (int o = 0; o < 2; ++o) {
        int ot = wid * 2 + o;
        bf16x8 bfr = *(const bf16x8*)&fw1r[(size_t)(ot * 16 + l4) * 1152 + kk9 * 128 + kc * 32 + g4 * 8];
        acc[o] = MFMA16(af, bfr, acc[o]);
      }
    }
  }
  int blk = b * 256 + pc;
#pragma unroll
  for (int o = 0; o < 2; ++o) {
    int ot = wid * 2 + o;
    float bias = fb1[ot * 16 + l4];
    float s = 0.f, s2 = 0.f;
#pragma unroll
    for (int r = 0; r < 4; ++r) {
      float v = acc[o][r] + bias;
      y[((size_t)(b << 12) + p0 + g4 * 4 + r) * 64 + ot * 16 + l4] = v;
      s += v;
      s2 += v * v;
    }
    s += __shfl_xor(s, 16);
    s += __shfl_xor(s, 32);
    s2 += __shfl_xor(s2, 16);
    s2 += __shfl_xor(s2, 32);
    if (lane < 16) {
      int ch = ot * 16 + lane;
      part[(size_t)ch * 1024 + blk] = s;
      part[65536 + (size_t)ch * 1024 + blk] = s2;
    }
  }
}

// --------------------------- K8: BatchNorm finalize ------------------------
// 64 blocks (one per channel) x 256 thr; coalesced reads; LDS tree reduce.
__global__ void k_bnfin(const float* part, const float* bng, const float* bnb,
                        float* bnA, float* bnB) {
  __shared__ float red[2][256];
  int o = blockIdx.x, t = threadIdx.x;
  float s = 0.f, s2 = 0.f;
#pragma unroll
  for (int k = 0; k < 4; ++k) {
    s += part[(size_t)o * 1024 + k * 256 + t];
    s2 += part[65536 + (size_t)o * 1024 + k * 256 + t];
  }
  red[0][t] = s;
  red[1][t] = s2;
  __syncthreads();
#pragma unroll
  for (int off = 128; off >= 1; off >>= 1) {
    if (t < off) {
      red[0][t] += red[0][t + off];
      red[1][t] += red[1][t + off];
    }
    __syncthreads();
  }
  if (t == 0) {
    float mean = red[0][0] * (1.0f / 16384.0f);
    float var = red[1][0] * (1.0f / 16384.0f) - mean * mean;
    float g = bng[o] * rsqrtf(var + 1e-5f);
    bnA[o] = g;
    bnB[o] = bnb[o] - mean * g;
  }
}

// --------------------------- K9: BN + ReLU + 1x1 conv ----------------------
// Grid (256 pc, 4 b), 128 thr = 2 waves; wave wid handles mt {wid*2, wid*2+1}.
__global__ __launch_bounds__(128) void k_final(const float* y, const unsigned short* fw2b,
                                               const float* bnA, const float* bnB,
                                               const float* fb2, float* out) {
  int pc = blockIdx.x, b = blockIdx.y;
  int lane = threadIdx.x & 63, wid = threadIdx.x >> 6;
  int l4 = lane & 15, g4 = lane >> 4;
  int p0 = pc * 16;

  bf16x8 afw[2][2];
#pragma unroll
  for (int m = 0; m < 2; ++m)
#pragma unroll
    for (int kc = 0; kc < 2; ++kc)
      afw[m][kc] = *(const bf16x8*)&fw2b[((wid * 2 + m) * 16 + l4) * 64 + kc * 32 + g4 * 8];
  float a8[2][8], b8[2][8];
#pragma unroll
  for (int kc = 0; kc < 2; ++kc)
#pragma unroll
    for (int e = 0; e < 8; ++e) {
      int c = kc * 32 + g4 * 8 + e;
      a8[kc][e] = bnA[c];
      b8[kc][e] = bnB[c];
    }
  float fbv[2][4];
#pragma unroll
  for (int m = 0; m < 2; ++m)
#pragma unroll
    for (int r = 0; r < 4; ++r) fbv[m][r] = fb2[(wid * 2 + m) * 16 + g4 * 4 + r];

  f32x4 acc[2];
#pragma unroll
  for (int m = 0; m < 2; ++m) acc[m] = f32x4{0.f, 0.f, 0.f, 0.f};

#pragma unroll
  for (int kc = 0; kc < 2; ++kc) {
    const float* yrow = &y[((size_t)(b << 12) + p0 + l4) * 64 + kc * 32 + g4 * 8];
    float4 y0 = *(const float4*)yrow;
    float4 y1 = *(const float4*)(yrow + 4);
    float zv[8] = {y0.x, y0.y, y0.z, y0.w, y1.x, y1.y, y1.z, y1.w};
    bf16x8 zf;
#pragma unroll
    for (int e = 0; e < 8; ++e)
      zf[e] = (short)f2bf(fmaxf(zv[e] * a8[kc][e] + b8[kc][e], 0.f));
#pragma unroll
    for (int m = 0; m < 2; ++m) acc[m] = MFMA16(afw[m][kc], zf, acc[m]);
  }
#pragma unroll
  for (int m = 0; m < 2; ++m)
#pragma unroll
    for (int r = 0; r < 4; ++r)
      out[((size_t)b * 64 + (wid * 2 + m) * 16 + g4 * 4 + r) * (size_t)S_ + p0 + l4] =
          acc[m][r] + fbv[m][r];
}

// --------------------------- host launcher ---------------------------------
extern "C" void kernel_launch(void* const* d_in, const int* in_sizes, int n_in,
                              void* d_out, int out_size, void* d_ws, size_t ws_size,
                              hipStream_t stream) {
  const float* x_s2 = (const float*)d_in[0];
  const float* x_dem = (const float*)d_in[1];
  const float* wq1 = (const float*)d_in[2];
  const float* bq1 = (const float*)d_in[3];
  const float* wk1 = (const float*)d_in[4];
  const float* bk1 = (const float*)d_in[5];
  const float* wv1 = (const float*)d_in[6];
  const float* bv1 = (const float*)d_in[7];
  const float* wq2 = (const float*)d_in[8];
  const float* bq2 = (const float*)d_in[9];
  const float* wk2 = (const float*)d_in[10];
  const float* bk2 = (const float*)d_in[11];
  const float* wv2 = (const float*)d_in[12];
  const float* bv2 = (const float*)d_in[13];
  const float* ln_s2_w = (const float*)d_in[14];
  const float* ln_s2_b = (const float*)d_in[15];
  const float* ln_dem_w = (const float*)d_in[16];
  const float* ln_dem_b = (const float*)d_in[17];
  const float* fw1 = (const float*)d_in[18];
  const float* fb1 = (const float*)d_in[19];
  const float* bn_g = (const float*)d_in[20];
  const float* bn_b = (const float*)d_in[21];
  const float* fw2 = (const float*)d_in[22];
  const float* fb2 = (const float*)d_in[23];

  char* ws = (char*)d_ws;
  unsigned short* xT = (unsigned short*)(ws + OFF_XT);
  unsigned short* wbuf = (unsigned short*)(ws + OFF_WB);
  unsigned short* fw1r = (unsigned short*)(ws + OFF_FW1R);
  unsigned short* Qf = (unsigned short*)(ws + OFF_QT);
  unsigned short* Kf = (unsigned short*)(ws + OFF_KT);
  unsigned short* Vf = (unsigned short*)(ws + OFF_V);
  unsigned short* comb = (unsigned short*)(ws + OFF_COMB);
  float* ybuf = (float*)(ws + OFF_Y);
  float* part = (float*)(ws + OFF_PART);
  float* bnA = (float*)(ws + OFF_BNA);
  float* bnB = (float*)(ws + OFF_BNB);

  k_prep<<<912, 256, 0, stream>>>(wq1, wk1, wv1, wq2, wk2, wv2, fw2, fw1,
                                  x_s2, x_dem, wbuf, fw1r, xT);
  k_proj<<<dim3(64, 4, 2), 256, 0, stream>>>(xT, wbuf, bq1, bk1, bv1,
                                             bq2, bk2, bv2, Qf, Kf, Vf);
  k_attn<<<dim3(8, 64), 384, 0, stream>>>(Qf, Kf, Vf, x_s2, x_dem,
                                          ln_s2_w, ln_s2_b, ln_dem_w, ln_dem_b,
                                          comb);
  k_conv3<<<dim3(256, 4), 128, 0, stream>>>(comb, fw1r, fb1, ybuf, part);
  k_bnfin<<<64, 256, 0, stream>>>(part, bn_g, bn_b, bnA, bnB);
  k_final<<<dim3(256, 4), 128, 0, stream>>>(ybuf, wbuf + 6 * 4096, bnA, bnB, fb2,
                                            (float*)d_out);
}

// Round 15
// 95.222 us; speedup vs baseline: 1.6469x; 1.6469x over previous
//
#include <hip/hip_runtime.h>
#include <hip/hip_bf16.h>

// ---------------------------------------------------------------------------
// BidirectionalCrossAttention on MI355X.
// R15: k_attn reverted to R12 exactly (41.6us; the j64+2-deep-prefetch loop
// fits only 2 waves/SIMD -- 3/SIMD spills (R10,R14), cross-block fences kill
// L2 (R13)). Pipeline win instead: x-transpose fused into k_proj (both dirs
// per block from two LDS-resident bf16 tiles) -> xT intermediate deleted
// (saves 4MB write + 8MB read + 512 transpose blocks). k_prep weights-only.
// ---------------------------------------------------------------------------

using bf16x8 = __attribute__((ext_vector_type(8))) short;
using f32x4  = __attribute__((ext_vector_type(4))) float;
using f32x16 = __attribute__((ext_vector_type(16))) float;
typedef unsigned int uint2v __attribute__((ext_vector_type(2)));

#define MFMA16(a, b, c) __builtin_amdgcn_mfma_f32_16x16x32_bf16((a), (b), (c), 0, 0, 0)
#define MFMA32(a, b, c) __builtin_amdgcn_mfma_f32_32x32x16_bf16((a), (b), (c), 0, 0, 0)

constexpr int B_ = 4, C_ = 64, S_ = 4096;
constexpr float kQS = 0.18033688f;  // 0.125 * log2(e), folded into wq/bq

// workspace byte offsets
constexpr size_t OFF_WB   = 0;                        // 7*4096 ushort
constexpr size_t OFF_FW1R = OFF_WB + 64 * 1024;       // 64*1152 ushort
constexpr size_t OFF_QT   = OFF_FW1R + 160 * 1024;    // Qf fragment-major
constexpr size_t OFF_KT   = OFF_QT + 4u * 1024 * 1024;   // Kf
constexpr size_t OFF_V    = OFF_KT + 4u * 1024 * 1024;   // Vf
constexpr size_t OFF_COMB = OFF_V + 4u * 1024 * 1024; // B*S*128 ushort
constexpr size_t OFF_Y    = OFF_COMB + 4u * 1024 * 1024; // B*S*64 f32
constexpr size_t OFF_PART = OFF_Y + 4u * 1024 * 1024; // 2*64*1024 f32 = 512KB
constexpr size_t OFF_BNA  = OFF_PART + 512 * 1024;
constexpr size_t OFF_BNB  = OFF_BNA + 1024;

__device__ __forceinline__ unsigned short f2bf(float f) {
  unsigned int u = __float_as_uint(f);
  unsigned int r = (u + 0x7fffu + ((u >> 16) & 1u)) >> 16;
  return (unsigned short)r;
}
__device__ __forceinline__ unsigned int cvt_pk_bf16(float lo, float hi) {
  unsigned int r;
  asm("v_cvt_pk_bf16_f32 %0, %1, %2" : "=v"(r) : "v"(lo), "v"(hi));
  return r;
}
__device__ __forceinline__ float fast_exp2(float x) {
#if __has_builtin(__builtin_amdgcn_exp2f)
  return __builtin_amdgcn_exp2f(x);
#else
  return exp2f(x);
#endif
}
__device__ __forceinline__ void plswap(unsigned int& a, unsigned int& b) {
  uint2v r = __builtin_amdgcn_permlane32_swap(a, b, false, false);
  a = r[0];
  b = r[1];
}

// exp2 of 16 S-values, accumulate denominator, build 2 PV B-fragments
// (i-halves) via cvt_pk + permlane32_swap. Lane layout: col j = lane&31,
// rows i = (reg&3) + 8*(reg>>2) + 4*(lane>>5).  [verified R4-R12]
__device__ __forceinline__ void build_pv_frags(const f32x16 s, float& lsum,
                                               bf16x8* out) {
  float p[16];
#pragma unroll
  for (int r = 0; r < 16; ++r) p[r] = fast_exp2(s[r]);
  lsum += (((p[0] + p[1]) + (p[2] + p[3])) + ((p[4] + p[5]) + (p[6] + p[7]))) +
          (((p[8] + p[9]) + (p[10] + p[11])) + ((p[12] + p[13]) + (p[14] + p[15])));
#pragma unroll
  for (int h = 0; h < 2; ++h) {
    unsigned int X  = cvt_pk_bf16(p[8 * h + 0], p[8 * h + 1]);
    unsigned int X2 = cvt_pk_bf16(p[8 * h + 2], p[8 * h + 3]);
    unsigned int Y  = cvt_pk_bf16(p[8 * h + 4], p[8 * h + 5]);
    unsigned int Y2 = cvt_pk_bf16(p[8 * h + 6], p[8 * h + 7]);
    plswap(X, Y);
    plswap(X2, Y2);
    union { unsigned int u[4]; bf16x8 v; } bb;
    bb.u[0] = X; bb.u[1] = X2; bb.u[2] = Y; bb.u[3] = Y2;
    out[h] = bb.v;
  }
}

// --------------------------- K0: weight prep (weights only) ----------------
__global__ void k_prep(const float* wq1, const float* wk1, const float* wv1,
                       const float* wq2, const float* wk2, const float* wv2,
                       const float* fw2, const float* fw1,
                       unsigned short* wb, unsigned short* fw1r) {
  int g = blockIdx.x * 256 + threadIdx.x;
  if (g < 7 * 4096) {
    int m = g >> 12, idx = g & 4095;
    const float* src[7] = {wq1, wk1, wv1, wq2, wk2, wv2, fw2};
    float sc = (m == 0 || m == 3) ? kQS : 1.0f;  // fold softmax scale into Q
    wb[g] = f2bf(src[m][idx] * sc);
  } else {
    int t = g - 7 * 4096;
    if (t < 64 * 1152) {
      int o = t / 1152, kk = t % 1152;
      int dydx = kk >> 7, ci = kk & 127;
      fw1r[t] = f2bf(fw1[o * 1152 + ci * 9 + dydx]);
    }
  }
}

// --------------------------- K2: fused transpose + projections -------------
// Block (pc,b): stage xs2/xdem 64x64 f32 tiles, transpose to bf16 LDS tiles,
// then Q,K,V for BOTH dirs. Outputs fragment-major:
// Qf/Kf: [cchunk 4][p 4096][c 16] ushort; Vf: [ichunk 256][c 64][i 16].
__global__ __launch_bounds__(256) void k_proj(
    const float* xs2, const float* xdem, const unsigned short* wb,
    const float* bq1, const float* bk1, const float* bv1,
    const float* bq2, const float* bk2, const float* bv2,
    unsigned short* Qf, unsigned short* Kf, unsigned short* Vf) {
  __shared__ float fst[64][65];                   // 16640 B
  __shared__ __align__(16) unsigned short t2[2][64][72];  // 18432 B
  int pc = blockIdx.x, b = blockIdx.y;
  int tid = threadIdx.x;
  int p0 = pc * 64;
  for (int tz = 0; tz < 2; ++tz) {
    const float* src = tz ? xdem : xs2;
#pragma unroll
    for (int k = 0; k < 16; ++k) {
      int idx = k * 256 + tid;
      int c = idx >> 6, pp = idx & 63;
      fst[c][pp] = src[((size_t)(b * 64 + c) << 12) + p0 + pp];
    }
    __syncthreads();
#pragma unroll
    for (int k = 0; k < 4; ++k) {
      int p = (tid >> 4) + k * 16;
      int c0 = (tid & 15) * 4;
#pragma unroll
      for (int e = 0; e < 4; ++e) t2[tz][p][c0 + e] = f2bf(fst[c0 + e][p]);
    }
    __syncthreads();
  }

  int lane = tid & 63, wid = tid >> 6;
  int l4 = lane & 15, g4 = lane >> 4;
  int prow = wid * 16 + l4;
  int pbase = p0 + wid * 16;
  bf16x8 aS[2], aD[2];
#pragma unroll
  for (int kc = 0; kc < 2; ++kc) {
    aS[kc] = *(const bf16x8*)&t2[0][prow][kc * 32 + g4 * 8];
    aD[kc] = *(const bf16x8*)&t2[1][prow][kc * 32 + g4 * 8];
  }

#pragma unroll
  for (int dir = 0; dir < 2; ++dir) {
    const bf16x8* aq = dir ? aD : aS;
    const bf16x8* akv = dir ? aS : aD;
    size_t dbOff = ((size_t)dir * B_ + b) * (size_t)(S_ * C_);
    const float* bq = dir ? bq2 : bq1;
    const float* bk = dir ? bk2 : bk1;
    const float* bv = dir ? bv2 : bv1;

    // Q and K -> fragment-major [nt][p][l4]
#pragma unroll
    for (int prod = 0; prod < 2; ++prod) {
      const unsigned short* wm = wb + (dir * 3 + prod) * 4096;
      unsigned short* dst = (prod == 0 ? Qf : Kf) + dbOff;
      const float* bp = (prod == 0) ? bq : bk;
      float bscale = (prod == 0) ? kQS : 1.0f;
      const bf16x8* af = (prod == 0) ? aq : akv;
#pragma unroll
      for (int nt = 0; nt < 4; ++nt) {
        bf16x8 wf0 = *(const bf16x8*)&wm[(nt * 16 + l4) * 64 + g4 * 8];
        bf16x8 wf1 = *(const bf16x8*)&wm[(nt * 16 + l4) * 64 + 32 + g4 * 8];
        f32x4 acc = {0.f, 0.f, 0.f, 0.f};
        acc = MFMA16(af[0], wf0, acc);
        acc = MFMA16(af[1], wf1, acc);
        float bias_c = bp[nt * 16 + l4] * bscale;
#pragma unroll
        for (int r = 0; r < 4; ++r)
          dst[(size_t)nt * 65536 + (size_t)(pbase + g4 * 4 + r) * 16 + l4] =
              f2bf(acc[r] + bias_c);
      }
    }
    // V -> fragment-major [p>>4][c][p&15]
    {
      const unsigned short* wm = wb + (dir * 3 + 2) * 4096;
      unsigned short* dst = Vf + dbOff;
#pragma unroll
      for (int mt = 0; mt < 4; ++mt) {
        bf16x8 wf0 = *(const bf16x8*)&wm[(mt * 16 + l4) * 64 + g4 * 8];
        bf16x8 wf1 = *(const bf16x8*)&wm[(mt * 16 + l4) * 64 + 32 + g4 * 8];
        f32x4 acc = {0.f, 0.f, 0.f, 0.f};
        acc = MFMA16(wf0, akv[0], acc);
        acc = MFMA16(wf1, akv[1], acc);
#pragma unroll
        for (int r = 0; r < 4; ++r) {
          int c = mt * 16 + g4 * 4 + r;
          dst[(size_t)(pbase >> 4) * 1024 + c * 16 + l4] = f2bf(acc[r] + bv[c]);
        }
      }
    }
  }
}

// --------------------------- K5: fused flash attention (LDS-free, j64) -----
// Grid (8 bd, 64 jb): linear%8 = bd -> XCD-local Qf/Kf/Vf (1.5MB < 4MB L2).
// 256 thr = 4 waves; wave wid owns i-range [wid*1024, +1024) (32 tiles),
// j-tile 64 (two j-groups share each K/V fragment read). 2-deep register
// prefetch (A/B sets) hides L2 latency. LDS only for epilogue reduce.
// [R12-exact: 41.6us, 2 waves/SIMD; more waves spills (R10/R14)]
constexpr int TST = 72;

__global__ __launch_bounds__(256, 2) void k_attn(
    const unsigned short* Qf, const unsigned short* Kf, const unsigned short* Vf,
    const float* xs2, const float* xdem,
    const float* lnw_s2, const float* lnb_s2,
    const float* lnw_dem, const float* lnb_dem,
    unsigned short* comb) {
  __shared__ __align__(16) char smem[34816];  // 2 x 16384 slots + Lp 2048
  const f32x16 kZero16 = {0.f, 0.f, 0.f, 0.f, 0.f, 0.f, 0.f, 0.f,
                          0.f, 0.f, 0.f, 0.f, 0.f, 0.f, 0.f, 0.f};
  int bd = blockIdx.x, jb = blockIdx.y;
  int dir = bd >> 2, b = bd & 3;
  int lane = threadIdx.x & 63, wid = threadIdx.x >> 6;
  int l5 = lane & 31;
  int h = lane >> 5;
  int hi8 = h * 8, hi4 = h * 4;
  size_t dbOff = (size_t)bd * (size_t)(S_ * C_);
  const unsigned short* qp = Qf + dbOff;
  const unsigned short* kp = Kf + dbOff;
  const unsigned short* vp = Vf + dbOff;

  int jbase = jb * 64;
  // resident Q fragments for 2 j-groups (coalesced from fragment-major Qf)
  bf16x8 qf[2][4];
#pragma unroll
  for (int jg = 0; jg < 2; ++jg)
#pragma unroll
    for (int kc = 0; kc < 4; ++kc)
      qf[jg][kc] = *(const bf16x8*)&qp[(size_t)kc * 65536 +
                                       (size_t)(jbase + jg * 32 + l5) * 16 + hi8];

  f32x16 acc00 = kZero16, acc01 = kZero16, acc10 = kZero16, acc11 = kZero16;
  float lsum0 = 0.f, lsum1 = 0.f;
  int ibeg = wid * 1024;

#define LOADT(AK, AV, I0)                                                    \
  {                                                                          \
    int i0_ = (I0);                                                          \
    _Pragma("unroll") for (int k_ = 0; k_ < 4; ++k_)                         \
        (AK)[k_] = *(const bf16x8*)&kp[(size_t)k_ * 65536 +                  \
                                       (size_t)(i0_ + l5) * 16 + hi8];       \
    int ic_ = i0_ >> 4;                                                      \
    (AV)[0] = *(const bf16x8*)&vp[(size_t)ic_ * 1024 + l5 * 16 + hi8];       \
    (AV)[1] = *(const bf16x8*)&vp[(size_t)(ic_ + 1) * 1024 + l5 * 16 + hi8]; \
    (AV)[2] = *(const bf16x8*)&vp[(size_t)ic_ * 1024 + (32 + l5) * 16 + hi8];\
    (AV)[3] = *(const bf16x8*)&vp[(size_t)(ic_ + 1) * 1024 + (32 + l5) * 16 + hi8];\
  }

#define TILE(AK, AV)                                                         \
  {                                                                          \
    f32x16 S0 = kZero16;                                                     \
    S0 = MFMA32((AK)[0], qf[0][0], S0);                                      \
    S0 = MFMA32((AK)[1], qf[0][1], S0);                                      \
    S0 = MFMA32((AK)[2], qf[0][2], S0);                                      \
    S0 = MFMA32((AK)[3], qf[0][3], S0);                                      \
    bf16x8 pb0[2];                                                           \
    build_pv_frags(S0, lsum0, pb0);                                          \
    f32x16 S1 = kZero16;                                                     \
    S1 = MFMA32((AK)[0], qf[1][0], S1);                                      \
    S1 = MFMA32((AK)[1], qf[1][1], S1);                                      \
    S1 = MFMA32((AK)[2], qf[1][2], S1);                                      \
    S1 = MFMA32((AK)[3], qf[1][3], S1);                                      \
    bf16x8 pb1[2];                                                           \
    build_pv_frags(S1, lsum1, pb1);                                          \
    acc00 = MFMA32((AV)[0], pb0[0], acc00);                                  \
    acc00 = MFMA32((AV)[1], pb0[1], acc00);                                  \
    acc01 = MFMA32((AV)[2], pb0[0], acc01);                                  \
    acc01 = MFMA32((AV)[3], pb0[1], acc01);                                  \
    acc10 = MFMA32((AV)[0], pb1[0], acc10);                                  \
    acc10 = MFMA32((AV)[1], pb1[1], acc10);                                  \
    acc11 = MFMA32((AV)[2], pb1[0], acc11);                                  \
    acc11 = MFMA32((AV)[3], pb1[1], acc11);                                  \
  }

  bf16x8 akA[4], avA[4], akB[4], avB[4];
  LOADT(akA, avA, ibeg)
  for (int t = 0; t < 32; t += 2) {
    LOADT(akB, avB, ibeg + ((t + 1) & 31) * 32)
    TILE(akA, avA)
    LOADT(akA, avA, ibeg + ((t + 2) & 31) * 32)
    TILE(akB, avB)
  }
#undef LOADT
#undef TILE

  // epilogue: reduce the 4 i-waves' partials (2 slots of 16KB)
  float* Lp = (float*)(smem + 32768);
  Lp[wid * 128 + lane] = lsum0;
  Lp[wid * 128 + 64 + lane] = lsum1;

#define STORE1(A_, CIDX, RG)                                              \
  {                                                                       \
    _Pragma("unroll") for (int q2 = 0; q2 < 4; ++q2) {                    \
      f32x4 tv = {(A_)[q2 * 4 + 0], (A_)[q2 * 4 + 1],                     \
                  (A_)[q2 * 4 + 2], (A_)[q2 * 4 + 3]};                    \
      *(f32x4*)&(RG)[((CIDX) * 4 + q2) * 256 + lane * 4] = tv;            \
    }                                                                     \
  }
#define ADD1(A_, CIDX, RR)                                                \
  {                                                                       \
    _Pragma("unroll") for (int q2 = 0; q2 < 4; ++q2) {                    \
      f32x4 tv = *(const f32x4*)&(RR)[((CIDX) * 4 + q2) * 256 + lane * 4];\
      _Pragma("unroll") for (int e = 0; e < 4; ++e) (A_)[q2 * 4 + e] += tv[e]; \
    }                                                                     \
  }
#define PUB(SLOT)                                                         \
  {                                                                       \
    float* rg_ = (float*)(smem + (size_t)(SLOT) * 16384);                 \
    STORE1(acc00, 0, rg_) STORE1(acc01, 1, rg_)                           \
    STORE1(acc10, 2, rg_) STORE1(acc11, 3, rg_)                           \
  }
#define ADDP(SLOT)                                                        \
  {                                                                       \
    const float* rr_ = (const float*)(smem + (size_t)(SLOT) * 16384);     \
    ADD1(acc00, 0, rr_) ADD1(acc01, 1, rr_)                               \
    ADD1(acc10, 2, rr_) ADD1(acc11, 3, rr_)                               \
  }

  if (wid >= 2) PUB(wid - 2)
  __syncthreads();
  if (wid < 2) ADDP(wid)
  __syncthreads();
  if (wid == 1) PUB(0)
  __syncthreads();
  if (wid != 0) return;
  ADDP(0)
#undef PUB
#undef ADDP
#undef STORE1
#undef ADD1

  // final wave: denominators, residual, LayerNorm, comb write for j64
  const float* xa = (dir == 0 ? xs2 : xdem) + (size_t)b * C_ * S_;
  const float* lw = (dir == 0) ? lnw_s2 : lnw_dem;
  const float* lbp = (dir == 0) ? lnb_s2 : lnb_dem;
  unsigned short* T = (unsigned short*)smem;  // slot region free now

#pragma unroll
  for (int jg = 0; jg < 2; ++jg) {
    float ls = 0.f;
#pragma unroll
    for (int w = 0; w < 4; ++w) ls += Lp[w * 128 + jg * 64 + lane];
    ls += __shfl_xor(ls, 32);
    float linv = 1.0f / ls;
    int jcol = jbase + jg * 32 + l5;

    float vals[32];
    float s1 = 0.f, s2 = 0.f;
#pragma unroll
    for (int ct = 0; ct < 2; ++ct)
#pragma unroll
      for (int reg = 0; reg < 16; ++reg) {
        int c = ct * 32 + (reg & 3) + 8 * (reg >> 2) + hi4;
        float a_ = (jg == 0) ? (ct == 0 ? acc00[reg] : acc01[reg])
                             : (ct == 0 ? acc10[reg] : acc11[reg]);
        float v = a_ * linv + xa[(size_t)c * S_ + jcol];
        vals[ct * 16 + reg] = v;
        s1 += v;
        s2 += v * v;
      }
    s1 += __shfl_xor(s1, 32);
    s2 += __shfl_xor(s2, 32);
    float mean = s1 * (1.0f / 64.0f);
    float var = s2 * (1.0f / 64.0f) - mean * mean;
    float rstd = rsqrtf(var + 1e-5f);

#pragma unroll
    for (int ct = 0; ct < 2; ++ct)
#pragma unroll
      for (int q2 = 0; q2 < 4; ++q2)
#pragma unroll
        for (int pp = 0; pp < 2; ++pp) {
          int r0 = q2 * 4 + pp * 2;
          int c0 = ct * 32 + 8 * q2 + hi4 + pp * 2;
          float x0 = (vals[ct * 16 + r0 + 0] - mean) * rstd * lw[c0 + 0] + lbp[c0 + 0];
          float x1 = (vals[ct * 16 + r0 + 1] - mean) * rstd * lw[c0 + 1] + lbp[c0 + 1];
          *(unsigned int*)&T[l5 * TST + c0] = cvt_pk_bf16(x0, x1);
        }
    int j_l = lane >> 1, cc = (lane & 1) * 32;
    unsigned short* cb =
        comb + ((size_t)b * S_ + jbase + jg * 32 + j_l) * 128 + dir * 64 + cc;
    const unsigned short* ts = &T[j_l * TST + cc];
#pragma unroll
    for (int q = 0; q < 4; ++q) {
      uint4 tq = *(const uint4*)&ts[q * 8];
      *(uint4*)&cb[q * 8] = tq;
    }
  }
}

// --------------------------- K6: 3x3 conv + fused BN partial sums ----------
// Grid (256 pc, 4 b), 128 thr = 2 waves; wave wid handles oc [wid*32,+32).
// Partials written channel-major: part[ch][blk], part2 at +65536 floats.
__global__ __launch_bounds__(128) void k_conv3(const unsigned short* comb,
                                               const unsigned short* fw1r,
                                               const float* fb1, float* y,
                                               float* part) {
  int pc = blockIdx.x, b = blockIdx.y;
  int lane = threadIdx.x & 63, wid = threadIdx.x >> 6;
  int l4 = lane & 15, g4 = lane >> 4;
  int p0 = pc * 16;
  int p_l = p0 + l4;
  int py0 = p_l >> 6, px0 = p_l & 63;
  f32x4 acc[2];
#pragma unroll
  for (int o = 0; o < 2; ++o) acc[o] = f32x4{0.f, 0.f, 0.f, 0.f};

#pragma unroll
  for (int kk9 = 0; kk9 < 9; ++kk9) {
    int py = py0 + (kk9 / 3) - 1;
    int px = px0 + (kk9 % 3) - 1;
    bool ok = (py >= 0) && (py < 64) && (px >= 0) && (px < 64);
    const unsigned short* base = comb + ((size_t)(b << 12) + py * 64 + px) * 128;
#pragma unroll
    for (int kc = 0; kc < 4; ++kc) {
      bf16x8 af = {0, 0, 0, 0, 0, 0, 0, 0};
      if (ok) af = *(const bf16x8*)&base[kc * 32 + g4 * 8];
#pragma unroll
      for (int o = 0; o < 2; ++o) {
        int ot = wid * 2 + o;
        bf16x8 bfr = *(const bf16x8*)&fw1r[(size_t)(ot * 16 + l4) * 1152 + kk9 * 128 + kc * 32 + g4 * 8];
        acc[o] = MFMA16(af, bfr, acc[o]);
      }
    }
  }
  int blk = b * 256 + pc;
#pragma unroll
  for (int o = 0; o < 2; ++o) {
    int ot = wid * 2 + o;
    float bias = fb1[ot * 16 + l4];
    float s = 0.f, s2 = 0.f;
#pragma unroll
    for (int r = 0; r < 4; ++r) {
      float v = acc[o][r] + bias;
      y[((size_t)(b << 12) + p0 + g4 * 4 + r) * 64 + ot * 16 + l4] = v;
      s += v;
      s2 += v * v;
    }
    s += __shfl_xor(s, 16);
    s += __shfl_xor(s, 32);
    s2 += __shfl_xor(s2, 16);
    s2 += __shfl_xor(s2, 32);
    if (lane < 16) {
      int ch = ot * 16 + lane;
      part[(size_t)ch * 1024 + blk] = s;
      part[65536 + (size_t)ch * 1024 + blk] = s2;
    }
  }
}

// --------------------------- K8: BatchNorm finalize ------------------------
// 64 blocks (one per channel) x 256 thr; coalesced reads; LDS tree reduce.
__global__ void k_bnfin(const float* part, const float* bng, const float* bnb,
                        float* bnA, float* bnB) {
  __shared__ float red[2][256];
  int o = blockIdx.x, t = threadIdx.x;
  float s = 0.f, s2 = 0.f;
#pragma unroll
  for (int k = 0; k < 4; ++k) {
    s += part[(size_t)o * 1024 + k * 256 + t];
    s2 += part[65536 + (size_t)o * 1024 + k * 256 + t];
  }
  red[0][t] = s;
  red[1][t] = s2;
  __syncthreads();
#pragma unroll
  for (int off = 128; off >= 1; off >>= 1) {
    if (t < off) {
      red[0][t] += red[0][t + off];
      red[1][t] += red[1][t + off];
    }
    __syncthreads();
  }
  if (t == 0) {
    float mean = red[0][0] * (1.0f / 16384.0f);
    float var = red[1][0] * (1.0f / 16384.0f) - mean * mean;
    float g = bng[o] * rsqrtf(var + 1e-5f);
    bnA[o] = g;
    bnB[o] = bnb[o] - mean * g;
  }
}

// --------------------------- K9: BN + ReLU + 1x1 conv ----------------------
// Grid (256 pc, 4 b), 128 thr = 2 waves; wave wid handles mt {wid*2, wid*2+1}.
__global__ __launch_bounds__(128) void k_final(const float* y, const unsigned short* fw2b,
                                               const float* bnA, const float* bnB,
                                               const float* fb2, float* out) {
  int pc = blockIdx.x, b = blockIdx.y;
  int lane = threadIdx.x & 63, wid = threadIdx.x >> 6;
  int l4 = lane & 15, g4 = lane >> 4;
  int p0 = pc * 16;

  bf16x8 afw[2][2];
#pragma unroll
  for (int m = 0; m < 2; ++m)
#pragma unroll
    for (int kc = 0; kc < 2; ++kc)
      afw[m][kc] = *(const bf16x8*)&fw2b[((wid * 2 + m) * 16 + l4) * 64 + kc * 32 + g4 * 8];
  float a8[2][8], b8[2][8];
#pragma unroll
  for (int kc = 0; kc < 2; ++kc)
#pragma unroll
    for (int e = 0; e < 8; ++e) {
      int c = kc * 32 + g4 * 8 + e;
      a8[kc][e] = bnA[c];
      b8[kc][e] = bnB[c];
    }
  float fbv[2][4];
#pragma unroll
  for (int m = 0; m < 2; ++m)
#pragma unroll
    for (int r = 0; r < 4; ++r) fbv[m][r] = fb2[(wid * 2 + m) * 16 + g4 * 4 + r];

  f32x4 acc[2];
#pragma unroll
  for (int m = 0; m < 2; ++m) acc[m] = f32x4{0.f, 0.f, 0.f, 0.f};

#pragma unroll
  for (int kc = 0; kc < 2; ++kc) {
    const float* yrow = &y[((size_t)(b << 12) + p0 + l4) * 64 + kc * 32 + g4 * 8];
    float4 y0 = *(const float4*)yrow;
    float4 y1 = *(const float4*)(yrow + 4);
    float zv[8] = {y0.x, y0.y, y0.z, y0.w, y1.x, y1.y, y1.z, y1.w};
    bf16x8 zf;
#pragma unroll
    for (int e = 0; e < 8; ++e)
      zf[e] = (short)f2bf(fmaxf(zv[e] * a8[kc][e] + b8[kc][e], 0.f));
#pragma unroll
    for (int m = 0; m < 2; ++m) acc[m] = MFMA16(afw[m][kc], zf, acc[m]);
  }
#pragma unroll
  for (int m = 0; m < 2; ++m)
#pragma unroll
    for (int r = 0; r < 4; ++r)
      out[((size_t)b * 64 + (wid * 2 + m) * 16 + g4 * 4 + r) * (size_t)S_ + p0 + l4] =
          acc[m][r] + fbv[m][r];
}

// --------------------------- host launcher ---------------------------------
extern "C" void kernel_launch(void* const* d_in, const int* in_sizes, int n_in,
                              void* d_out, int out_size, void* d_ws, size_t ws_size,
                              hipStream_t stream) {
  const float* x_s2 = (const float*)d_in[0];
  const float* x_dem = (const float*)d_in[1];
  const float* wq1 = (const float*)d_in[2];
  const float* bq1 = (const float*)d_in[3];
  const float* wk1 = (const float*)d_in[4];
  const float* bk1 = (const float*)d_in[5];
  const float* wv1 = (const float*)d_in[6];
  const float* bv1 = (const float*)d_in[7];
  const float* wq2 = (const float*)d_in[8];
  const float* bq2 = (const float*)d_in[9];
  const float* wk2 = (const float*)d_in[10];
  const float* bk2 = (const float*)d_in[11];
  const float* wv2 = (const float*)d_in[12];
  const float* bv2 = (const float*)d_in[13];
  const float* ln_s2_w = (const float*)d_in[14];
  const float* ln_s2_b = (const float*)d_in[15];
  const float* ln_dem_w = (const float*)d_in[16];
  const float* ln_dem_b = (const float*)d_in[17];
  const float* fw1 = (const float*)d_in[18];
  const float* fb1 = (const float*)d_in[19];
  const float* bn_g = (const float*)d_in[20];
  const float* bn_b = (const float*)d_in[21];
  const float* fw2 = (const float*)d_in[22];
  const float* fb2 = (const float*)d_in[23];

  char* ws = (char*)d_ws;
  unsigned short* wbuf = (unsigned short*)(ws + OFF_WB);
  unsigned short* fw1r = (unsigned short*)(ws + OFF_FW1R);
  unsigned short* Qf = (unsigned short*)(ws + OFF_QT);
  unsigned short* Kf = (unsigned short*)(ws + OFF_KT);
  unsigned short* Vf = (unsigned short*)(ws + OFF_V);
  unsigned short* comb = (unsigned short*)(ws + OFF_COMB);
  float* ybuf = (float*)(ws + OFF_Y);
  float* part = (float*)(ws + OFF_PART);
  float* bnA = (float*)(ws + OFF_BNA);
  float* bnB = (float*)(ws + OFF_BNB);

  k_prep<<<400, 256, 0, stream>>>(wq1, wk1, wv1, wq2, wk2, wv2, fw2, fw1,
                                  wbuf, fw1r);
  k_proj<<<dim3(64, 4), 256, 0, stream>>>(x_s2, x_dem, wbuf, bq1, bk1, bv1,
                                          bq2, bk2, bv2, Qf, Kf, Vf);
  k_attn<<<dim3(8, 64), 256, 0, stream>>>(Qf, Kf, Vf, x_s2, x_dem,
                                          ln_s2_w, ln_s2_b, ln_dem_w, ln_dem_b,
                                          comb);
  k_conv3<<<dim3(256, 4), 128, 0, stream>>>(comb, fw1r, fb1, ybuf, part);
  k_bnfin<<<64, 256, 0, stream>>>(part, bn_g, bn_b, bnA, bnB);
  k_final<<<dim3(256, 4), 128, 0, stream>>>(ybuf, wbuf + 6 * 4096, bnA, bnB, fb2,
                                            (float*)d_out);
}

// Round 16
// 91.904 us; speedup vs baseline: 1.7063x; 1.0361x over previous
//
#include <hip/hip_runtime.h>
#include <hip/hip_bf16.h>

// ---------------------------------------------------------------------------
// BidirectionalCrossAttention on MI355X.
// R16 = R12 byte-for-byte (best measured: 92.1us). R13-R15 explored the
// remaining structural levers and all regressed:
//  - 4 waves/SIMD for the j64 loop spills the unified VGPR/AGPR file (R10,R14)
//  - cross-block flash combine needs device-scope fences -> XCD L2 flush (R13)
//  - fusing x-transpose into k_proj loses block-level parallelism (R15)
// k_attn (41.6us): LDS-free fragment-major loop, j64/wave, 2-deep register
// prefetch, 2 waves/SIMD, 72% issue-busy. Pipeline: ~50us across 5 kernels.
// ---------------------------------------------------------------------------

using bf16x8 = __attribute__((ext_vector_type(8))) short;
using f32x4  = __attribute__((ext_vector_type(4))) float;
using f32x16 = __attribute__((ext_vector_type(16))) float;
typedef unsigned int uint2v __attribute__((ext_vector_type(2)));

#define MFMA16(a, b, c) __builtin_amdgcn_mfma_f32_16x16x32_bf16((a), (b), (c), 0, 0, 0)
#define MFMA32(a, b, c) __builtin_amdgcn_mfma_f32_32x32x16_bf16((a), (b), (c), 0, 0, 0)

constexpr int B_ = 4, C_ = 64, S_ = 4096;
constexpr float kQS = 0.18033688f;  // 0.125 * log2(e), folded into wq/bq

// workspace byte offsets
constexpr size_t OFF_XT   = 0;                        // 2*B*S*C ushort = 4 MiB
constexpr size_t OFF_WB   = 4u * 1024 * 1024;         // 7*4096 ushort
constexpr size_t OFF_FW1R = OFF_WB + 64 * 1024;       // 64*1152 ushort
constexpr size_t OFF_QT   = OFF_FW1R + 160 * 1024;    // Qf fragment-major
constexpr size_t OFF_KT   = OFF_QT + 4u * 1024 * 1024;   // Kf
constexpr size_t OFF_V    = OFF_KT + 4u * 1024 * 1024;   // Vf
constexpr size_t OFF_COMB = OFF_V + 4u * 1024 * 1024; // B*S*128 ushort
constexpr size_t OFF_Y    = OFF_COMB + 4u * 1024 * 1024; // B*S*64 f32
constexpr size_t OFF_PART = OFF_Y + 4u * 1024 * 1024; // 2*64*1024 f32 = 512KB
constexpr size_t OFF_BNA  = OFF_PART + 512 * 1024;
constexpr size_t OFF_BNB  = OFF_BNA + 1024;

__device__ __forceinline__ unsigned short f2bf(float f) {
  unsigned int u = __float_as_uint(f);
  unsigned int r = (u + 0x7fffu + ((u >> 16) & 1u)) >> 16;
  return (unsigned short)r;
}
__device__ __forceinline__ unsigned int cvt_pk_bf16(float lo, float hi) {
  unsigned int r;
  asm("v_cvt_pk_bf16_f32 %0, %1, %2" : "=v"(r) : "v"(lo), "v"(hi));
  return r;
}
__device__ __forceinline__ float fast_exp2(float x) {
#if __has_builtin(__builtin_amdgcn_exp2f)
  return __builtin_amdgcn_exp2f(x);
#else
  return exp2f(x);
#endif
}
__device__ __forceinline__ void plswap(unsigned int& a, unsigned int& b) {
  uint2v r = __builtin_amdgcn_permlane32_swap(a, b, false, false);
  a = r[0];
  b = r[1];
}

// exp2 of 16 S-values, accumulate denominator, build 2 PV B-fragments
// (i-halves) via cvt_pk + permlane32_swap. Lane layout: col j = lane&31,
// rows i = (reg&3) + 8*(reg>>2) + 4*(lane>>5).  [verified R4-R15]
__device__ __forceinline__ void build_pv_frags(const f32x16 s, float& lsum,
                                               bf16x8* out) {
  float p[16];
#pragma unroll
  for (int r = 0; r < 16; ++r) p[r] = fast_exp2(s[r]);
  lsum += (((p[0] + p[1]) + (p[2] + p[3])) + ((p[4] + p[5]) + (p[6] + p[7]))) +
          (((p[8] + p[9]) + (p[10] + p[11])) + ((p[12] + p[13]) + (p[14] + p[15])));
#pragma unroll
  for (int h = 0; h < 2; ++h) {
    unsigned int X  = cvt_pk_bf16(p[8 * h + 0], p[8 * h + 1]);
    unsigned int X2 = cvt_pk_bf16(p[8 * h + 2], p[8 * h + 3]);
    unsigned int Y  = cvt_pk_bf16(p[8 * h + 4], p[8 * h + 5]);
    unsigned int Y2 = cvt_pk_bf16(p[8 * h + 6], p[8 * h + 7]);
    plswap(X, Y);
    plswap(X2, Y2);
    union { unsigned int u[4]; bf16x8 v; } bb;
    bb.u[0] = X; bb.u[1] = X2; bb.u[2] = Y; bb.u[3] = Y2;
    out[h] = bb.v;
  }
}

// --------------------------- K0: weight prep + x transpose -----------------
__global__ void k_prep(const float* wq1, const float* wk1, const float* wv1,
                       const float* wq2, const float* wk2, const float* wv2,
                       const float* fw2, const float* fw1,
                       const float* xs2, const float* xdem,
                       unsigned short* wb, unsigned short* fw1r,
                       unsigned short* xT) {
  __shared__ float lds[64][65];
  if (blockIdx.x < 400) {
    int g = blockIdx.x * 256 + threadIdx.x;
    if (g < 7 * 4096) {
      int m = g >> 12, idx = g & 4095;
      const float* src[7] = {wq1, wk1, wv1, wq2, wk2, wv2, fw2};
      float sc = (m == 0 || m == 3) ? kQS : 1.0f;  // fold softmax scale into Q
      wb[g] = f2bf(src[m][idx] * sc);
    } else {
      int t = g - 7 * 4096;
      if (t < 64 * 1152) {
        int o = t / 1152, kk = t % 1152;
        int dydx = kk >> 7, ci = kk & 127;
        fw1r[t] = f2bf(fw1[o * 1152 + ci * 9 + dydx]);
      }
    }
    return;
  }
  int bid = blockIdx.x - 400;
  int pt = bid & 63, b = (bid >> 6) & 3, tz = bid >> 8;
  int tid = threadIdx.x;
  const float* src = (tz == 0) ? xs2 : xdem;
  int p0 = pt * 64;
#pragma unroll
  for (int k = 0; k < 16; ++k) {
    int idx = k * 256 + tid;
    int c = idx >> 6, pp = idx & 63;
    lds[c][pp] = src[((size_t)(b * 64 + c) << 12) + p0 + pp];
  }
  __syncthreads();
  unsigned short* dst = xT + (size_t)tz * (B_ * S_ * C_);
#pragma unroll
  for (int k = 0; k < 4; ++k) {
    int p = (tid >> 4) + k * 16;
    int c0 = (tid & 15) * 4;
    ushort4 v;
    v.x = f2bf(lds[c0 + 0][p]);
    v.y = f2bf(lds[c0 + 1][p]);
    v.z = f2bf(lds[c0 + 2][p]);
    v.w = f2bf(lds[c0 + 3][p]);
    *(ushort4*)&dst[((size_t)((b << 12) + p0 + p)) * 64 + c0] = v;
  }
}

// --------------------------- K2: projections (fragment-major outputs) ------
// Qf/Kf: [cchunk 4][p 4096][c 16] ushort; Vf: [ichunk 256][c 64][i 16].
__global__ __launch_bounds__(256) void k_proj(
    const unsigned short* xT, const unsigned short* wb,
    const float* bq1, const float* bk1, const float* bv1,
    const float* bq2, const float* bk2, const float* bv2,
    unsigned short* Qf, unsigned short* Kf, unsigned short* Vf) {
  int pc = blockIdx.x, b = blockIdx.y, dir = blockIdx.z;
  int lane = threadIdx.x & 63, wid = threadIdx.x >> 6;
  int l4 = lane & 15, g4 = lane >> 4;
  const unsigned short* xq =
      xT + ((size_t)(dir * B_ + b)) * (size_t)(S_ * C_);        // query src
  const unsigned short* xkv =
      xT + ((size_t)((1 - dir) * B_ + b)) * (size_t)(S_ * C_);  // key/val src
  size_t dbOff = ((size_t)dir * B_ + b) * (size_t)(S_ * C_);
  const float* bq = dir ? bq2 : bq1;
  const float* bk = dir ? bk2 : bk1;
  const float* bv = dir ? bv2 : bv1;
  int pbase = pc * 64 + wid * 16;

  bf16x8 aq[2], akv[2];
#pragma unroll
  for (int kc = 0; kc < 2; ++kc) {
    aq[kc] = *(const bf16x8*)&xq[(size_t)(pbase + l4) * 64 + kc * 32 + g4 * 8];
    akv[kc] = *(const bf16x8*)&xkv[(size_t)(pbase + l4) * 64 + kc * 32 + g4 * 8];
  }

  // Q and K -> fragment-major [nt][p][l4]
#pragma unroll
  for (int prod = 0; prod < 2; ++prod) {
    const unsigned short* wm = wb + (dir * 3 + prod) * 4096;
    unsigned short* dst = (prod == 0 ? Qf : Kf) + dbOff;
    const float* bp = (prod == 0) ? bq : bk;
    float bscale = (prod == 0) ? kQS : 1.0f;
    const bf16x8* af = (prod == 0) ? aq : akv;
#pragma unroll
    for (int nt = 0; nt < 4; ++nt) {
      bf16x8 wf0 = *(const bf16x8*)&wm[(nt * 16 + l4) * 64 + g4 * 8];
      bf16x8 wf1 = *(const bf16x8*)&wm[(nt * 16 + l4) * 64 + 32 + g4 * 8];
      f32x4 acc = {0.f, 0.f, 0.f, 0.f};
      acc = MFMA16(af[0], wf0, acc);
      acc = MFMA16(af[1], wf1, acc);
      float bias_c = bp[nt * 16 + l4] * bscale;
#pragma unroll
      for (int r = 0; r < 4; ++r)
        dst[(size_t)nt * 65536 + (size_t)(pbase + g4 * 4 + r) * 16 + l4] =
            f2bf(acc[r] + bias_c);
    }
  }
  // V -> fragment-major [p>>4][c][p&15]
  {
    const unsigned short* wm = wb + (dir * 3 + 2) * 4096;
    unsigned short* dst = Vf + dbOff;
#pragma unroll
    for (int mt = 0; mt < 4; ++mt) {
      bf16x8 wf0 = *(const bf16x8*)&wm[(mt * 16 + l4) * 64 + g4 * 8];
      bf16x8 wf1 = *(const bf16x8*)&wm[(mt * 16 + l4) * 64 + 32 + g4 * 8];
      f32x4 acc = {0.f, 0.f, 0.f, 0.f};
      acc = MFMA16(wf0, akv[0], acc);
      acc = MFMA16(wf1, akv[1], acc);
#pragma unroll
      for (int r = 0; r < 4; ++r) {
        int c = mt * 16 + g4 * 4 + r;
        dst[(size_t)(pbase >> 4) * 1024 + c * 16 + l4] = f2bf(acc[r] + bv[c]);
      }
    }
  }
}

// --------------------------- K5: fused flash attention (LDS-free, j64) -----
// Grid (8 bd, 64 jb): linear%8 = bd -> XCD-local Qf/Kf/Vf (1.5MB < 4MB L2).
// 256 thr = 4 waves; wave wid owns i-range [wid*1024, +1024) (32 tiles),
// j-tile 64 (two j-groups share each K/V fragment read). 2-deep register
// prefetch (A/B sets) hides L2 latency. LDS only for epilogue reduce.
constexpr int TST = 72;

__global__ __launch_bounds__(256, 2) void k_attn(
    const unsigned short* Qf, const unsigned short* Kf, const unsigned short* Vf,
    const float* xs2, const float* xdem,
    const float* lnw_s2, const float* lnb_s2,
    const float* lnw_dem, const float* lnb_dem,
    unsigned short* comb) {
  __shared__ __align__(16) char smem[34816];  // 2 x 16384 slots + Lp 2048
  const f32x16 kZero16 = {0.f, 0.f, 0.f, 0.f, 0.f, 0.f, 0.f, 0.f,
                          0.f, 0.f, 0.f, 0.f, 0.f, 0.f, 0.f, 0.f};
  int bd = blockIdx.x, jb = blockIdx.y;
  int dir = bd >> 2, b = bd & 3;
  int lane = threadIdx.x & 63, wid = threadIdx.x >> 6;
  int l5 = lane & 31;
  int h = lane >> 5;
  int hi8 = h * 8, hi4 = h * 4;
  size_t dbOff = (size_t)bd * (size_t)(S_ * C_);
  const unsigned short* qp = Qf + dbOff;
  const unsigned short* kp = Kf + dbOff;
  const unsigned short* vp = Vf + dbOff;

  int jbase = jb * 64;
  // resident Q fragments for 2 j-groups (coalesced from fragment-major Qf)
  bf16x8 qf[2][4];
#pragma unroll
  for (int jg = 0; jg < 2; ++jg)
#pragma unroll
    for (int kc = 0; kc < 4; ++kc)
      qf[jg][kc] = *(const bf16x8*)&qp[(size_t)kc * 65536 +
                                       (size_t)(jbase + jg * 32 + l5) * 16 + hi8];

  f32x16 acc00 = kZero16, acc01 = kZero16, acc10 = kZero16, acc11 = kZero16;
  float lsum0 = 0.f, lsum1 = 0.f;
  int ibeg = wid * 1024;

#define LOADT(AK, AV, I0)                                                    \
  {                                                                          \
    int i0_ = (I0);                                                          \
    _Pragma("unroll") for (int k_ = 0; k_ < 4; ++k_)                         \
        (AK)[k_] = *(const bf16x8*)&kp[(size_t)k_ * 65536 +                  \
                                       (size_t)(i0_ + l5) * 16 + hi8];       \
    int ic_ = i0_ >> 4;                                                      \
    (AV)[0] = *(const bf16x8*)&vp[(size_t)ic_ * 1024 + l5 * 16 + hi8];       \
    (AV)[1] = *(const bf16x8*)&vp[(size_t)(ic_ + 1) * 1024 + l5 * 16 + hi8]; \
    (AV)[2] = *(const bf16x8*)&vp[(size_t)ic_ * 1024 + (32 + l5) * 16 + hi8];\
    (AV)[3] = *(const bf16x8*)&vp[(size_t)(ic_ + 1) * 1024 + (32 + l5) * 16 + hi8];\
  }

#define TILE(AK, AV)                                                         \
  {                                                                          \
    f32x16 S0 = kZero16;                                                     \
    S0 = MFMA32((AK)[0], qf[0][0], S0);                                      \
    S0 = MFMA32((AK)[1], qf[0][1], S0);                                      \
    S0 = MFMA32((AK)[2], qf[0][2], S0);                                      \
    S0 = MFMA32((AK)[3], qf[0][3], S0);                                      \
    bf16x8 pb0[2];                                                           \
    build_pv_frags(S0, lsum0, pb0);                                          \
    f32x16 S1 = kZero16;                                                     \
    S1 = MFMA32((AK)[0], qf[1][0], S1);                                      \
    S1 = MFMA32((AK)[1], qf[1][1], S1);                                      \
    S1 = MFMA32((AK)[2], qf[1][2], S1);                                      \
    S1 = MFMA32((AK)[3], qf[1][3], S1);                                      \
    bf16x8 pb1[2];                                                           \
    build_pv_frags(S1, lsum1, pb1);                                          \
    acc00 = MFMA32((AV)[0], pb0[0], acc00);                                  \
    acc00 = MFMA32((AV)[1], pb0[1], acc00);                                  \
    acc01 = MFMA32((AV)[2], pb0[0], acc01);                                  \
    acc01 = MFMA32((AV)[3], pb0[1], acc01);                                  \
    acc10 = MFMA32((AV)[0], pb1[0], acc10);                                  \
    acc10 = MFMA32((AV)[1], pb1[1], acc10);                                  \
    acc11 = MFMA32((AV)[2], pb1[0], acc11);                                  \
    acc11 = MFMA32((AV)[3], pb1[1], acc11);                                  \
  }

  bf16x8 akA[4], avA[4], akB[4], avB[4];
  LOADT(akA, avA, ibeg)
  for (int t = 0; t < 32; t += 2) {
    LOADT(akB, avB, ibeg + ((t + 1) & 31) * 32)
    TILE(akA, avA)
    LOADT(akA, avA, ibeg + ((t + 2) & 31) * 32)
    TILE(akB, avB)
  }
#undef LOADT
#undef TILE

  // epilogue: reduce the 4 i-waves' partials (2 slots of 16KB)
  float* Lp = (float*)(smem + 32768);
  Lp[wid * 128 + lane] = lsum0;
  Lp[wid * 128 + 64 + lane] = lsum1;

#define STORE1(A_, CIDX, RG)                                              \
  {                                                                       \
    _Pragma("unroll") for (int q2 = 0; q2 < 4; ++q2) {                    \
      f32x4 tv = {(A_)[q2 * 4 + 0], (A_)[q2 * 4 + 1],                     \
                  (A_)[q2 * 4 + 2], (A_)[q2 * 4 + 3]};                    \
      *(f32x4*)&(RG)[((CIDX) * 4 + q2) * 256 + lane * 4] = tv;            \
    }                                                                     \
  }
#define ADD1(A_, CIDX, RR)                                                \
  {                                                                       \
    _Pragma("unroll") for (int q2 = 0; q2 < 4; ++q2) {                    \
      f32x4 tv = *(const f32x4*)&(RR)[((CIDX) * 4 + q2) * 256 + lane * 4];\
      _Pragma("unroll") for (int e = 0; e < 4; ++e) (A_)[q2 * 4 + e] += tv[e]; \
    }                                                                     \
  }
#define PUB(SLOT)                                                         \
  {                                                                       \
    float* rg_ = (float*)(smem + (size_t)(SLOT) * 16384);                 \
    STORE1(acc00, 0, rg_) STORE1(acc01, 1, rg_)                           \
    STORE1(acc10, 2, rg_) STORE1(acc11, 3, rg_)                           \
  }
#define ADDP(SLOT)                                                        \
  {                                                                       \
    const float* rr_ = (const float*)(smem + (size_t)(SLOT) * 16384);     \
    ADD1(acc00, 0, rr_) ADD1(acc01, 1, rr_)                               \
    ADD1(acc10, 2, rr_) ADD1(acc11, 3, rr_)                               \
  }

  if (wid >= 2) PUB(wid - 2)
  __syncthreads();
  if (wid < 2) ADDP(wid)
  __syncthreads();
  if (wid == 1) PUB(0)
  __syncthreads();
  if (wid != 0) return;
  ADDP(0)
#undef PUB
#undef ADDP
#undef STORE1
#undef ADD1

  // final wave: denominators, residual, LayerNorm, comb write for j64
  const float* xa = (dir == 0 ? xs2 : xdem) + (size_t)b * C_ * S_;
  const float* lw = (dir == 0) ? lnw_s2 : lnw_dem;
  const float* lbp = (dir == 0) ? lnb_s2 : lnb_dem;
  unsigned short* T = (unsigned short*)smem;  // slot region free now

#pragma unroll
  for (int jg = 0; jg < 2; ++jg) {
    float ls = 0.f;
#pragma unroll
    for (int w = 0; w < 4; ++w) ls += Lp[w * 128 + jg * 64 + lane];
    ls += __shfl_xor(ls, 32);
    float linv = 1.0f / ls;
    int jcol = jbase + jg * 32 + l5;

    float vals[32];
    float s1 = 0.f, s2 = 0.f;
#pragma unroll
    for (int ct = 0; ct < 2; ++ct)
#pragma unroll
      for (int reg = 0; reg < 16; ++reg) {
        int c = ct * 32 + (reg & 3) + 8 * (reg >> 2) + hi4;
        float a_ = (jg == 0) ? (ct == 0 ? acc00[reg] : acc01[reg])
                             : (ct == 0 ? acc10[reg] : acc11[reg]);
        float v = a_ * linv + xa[(size_t)c * S_ + jcol];
        vals[ct * 16 + reg] = v;
        s1 += v;
        s2 += v * v;
      }
    s1 += __shfl_xor(s1, 32);
    s2 += __shfl_xor(s2, 32);
    float mean = s1 * (1.0f / 64.0f);
    float var = s2 * (1.0f / 64.0f) - mean * mean;
    float rstd = rsqrtf(var + 1e-5f);

#pragma unroll
    for (int ct = 0; ct < 2; ++ct)
#pragma unroll
      for (int q2 = 0; q2 < 4; ++q2)
#pragma unroll
        for (int pp = 0; pp < 2; ++pp) {
          int r0 = q2 * 4 + pp * 2;
          int c0 = ct * 32 + 8 * q2 + hi4 + pp * 2;
          float x0 = (vals[ct * 16 + r0 + 0] - mean) * rstd * lw[c0 + 0] + lbp[c0 + 0];
          float x1 = (vals[ct * 16 + r0 + 1] - mean) * rstd * lw[c0 + 1] + lbp[c0 + 1];
          *(unsigned int*)&T[l5 * TST + c0] = cvt_pk_bf16(x0, x1);
        }
    int j_l = lane >> 1, cc = (lane & 1) * 32;
    unsigned short* cb =
        comb + ((size_t)b * S_ + jbase + jg * 32 + j_l) * 128 + dir * 64 + cc;
    const unsigned short* ts = &T[j_l * TST + cc];
#pragma unroll
    for (int q = 0; q < 4; ++q) {
      uint4 tq = *(const uint4*)&ts[q * 8];
      *(uint4*)&cb[q * 8] = tq;
    }
  }
}

// --------------------------- K6: 3x3 conv + fused BN partial sums ----------
// Grid (256 pc, 4 b), 128 thr = 2 waves; wave wid handles oc [wid*32,+32).
// Partials written channel-major: part[ch][blk], part2 at +65536 floats.
__global__ __launch_bounds__(128) void k_conv3(const unsigned short* comb,
                                               const unsigned short* fw1r,
                                               const float* fb1, float* y,
                                               float* part) {
  int pc = blockIdx.x, b = blockIdx.y;
  int lane = threadIdx.x & 63, wid = threadIdx.x >> 6;
  int l4 = lane & 15, g4 = lane >> 4;
  int p0 = pc * 16;
  int p_l = p0 + l4;
  int py0 = p_l >> 6, px0 = p_l & 63;
  f32x4 acc[2];
#pragma unroll
  for (int o = 0; o < 2; ++o) acc[o] = f32x4{0.f, 0.f, 0.f, 0.f};

#pragma unroll
  for (int kk9 = 0; kk9 < 9; ++kk9) {
    int py = py0 + (kk9 / 3) - 1;
    int px = px0 + (kk9 % 3) - 1;
    bool ok = (py >= 0) && (py < 64) && (px >= 0) && (px < 64);
    const unsigned short* base = comb + ((size_t)(b << 12) + py * 64 + px) * 128;
#pragma unroll
    for (int kc = 0; kc < 4; ++kc) {
      bf16x8 af = {0, 0, 0, 0, 0, 0, 0, 0};
      if (ok) af = *(const bf16x8*)&base[kc * 32 + g4 * 8];
#pragma unroll
      for (int o = 0; o < 2; ++o) {
        int ot = wid * 2 + o;
        bf16x8 bfr = *(const bf16x8*)&fw1r[(size_t)(ot * 16 + l4) * 1152 + kk9 * 128 + kc * 32 + g4 * 8];
        acc[o] = MFMA16(af, bfr, acc[o]);
      }
    }
  }
  int blk = b * 256 + pc;
#pragma unroll
  for (int o = 0; o < 2; ++o) {
    int ot = wid * 2 + o;
    float bias = fb1[ot * 16 + l4];
    float s = 0.f, s2 = 0.f;
#pragma unroll
    for (int r = 0; r < 4; ++r) {
      float v = acc[o][r] + bias;
      y[((size_t)(b << 12) + p0 + g4 * 4 + r) * 64 + ot * 16 + l4] = v;
      s += v;
      s2 += v * v;
    }
    s += __shfl_xor(s, 16);
    s += __shfl_xor(s, 32);
    s2 += __shfl_xor(s2, 16);
    s2 += __shfl_xor(s2, 32);
    if (lane < 16) {
      int ch = ot * 16 + lane;
      part[(size_t)ch * 1024 + blk] = s;
      part[65536 + (size_t)ch * 1024 + blk] = s2;
    }
  }
}

// --------------------------- K8: BatchNorm finalize ------------------------
// 64 blocks (one per channel) x 256 thr; coalesced reads; LDS tree reduce.
__global__ void k_bnfin(const float* part, const float* bng, const float* bnb,
                        float* bnA, float* bnB) {
  __shared__ float red[2][256];
  int o = blockIdx.x, t = threadIdx.x;
  float s = 0.f, s2 = 0.f;
#pragma unroll
  for (int k = 0; k < 4; ++k) {
    s += part[(size_t)o * 1024 + k * 256 + t];
    s2 += part[65536 + (size_t)o * 1024 + k * 256 + t];
  }
  red[0][t] = s;
  red[1][t] = s2;
  __syncthreads();
#pragma unroll
  for (int off = 128; off >= 1; off >>= 1) {
    if (t < off) {
      red[0][t] += red[0][t + off];
      red[1][t] += red[1][t + off];
    }
    __syncthreads();
  }
  if (t == 0) {
    float mean = red[0][0] * (1.0f / 16384.0f);
    float var = red[1][0] * (1.0f / 16384.0f) - mean * mean;
    float g = bng[o] * rsqrtf(var + 1e-5f);
    bnA[o] = g;
    bnB[o] = bnb[o] - mean * g;
  }
}

// --------------------------- K9: BN + ReLU + 1x1 conv ----------------------
// Grid (256 pc, 4 b), 128 thr = 2 waves; wave wid handles mt {wid*2, wid*2+1}.
__global__ __launch_bounds__(128) void k_final(const float* y, const unsigned short* fw2b,
                                               const float* bnA, const float* bnB,
                                               const float* fb2, float* out) {
  int pc = blockIdx.x, b = blockIdx.y;
  int lane = threadIdx.x & 63, wid = threadIdx.x >> 6;
  int l4 = lane & 15, g4 = lane >> 4;
  int p0 = pc * 16;

  bf16x8 afw[2][2];
#pragma unroll
  for (int m = 0; m < 2; ++m)
#pragma unroll
    for (int kc = 0; kc < 2; ++kc)
      afw[m][kc] = *(const bf16x8*)&fw2b[((wid * 2 + m) * 16 + l4) * 64 + kc * 32 + g4 * 8];
  float a8[2][8], b8[2][8];
#pragma unroll
  for (int kc = 0; kc < 2; ++kc)
#pragma unroll
    for (int e = 0; e < 8; ++e) {
      int c = kc * 32 + g4 * 8 + e;
      a8[kc][e] = bnA[c];
      b8[kc][e] = bnB[c];
    }
  float fbv[2][4];
#pragma unroll
  for (int m = 0; m < 2; ++m)
#pragma unroll
    for (int r = 0; r < 4; ++r) fbv[m][r] = fb2[(wid * 2 + m) * 16 + g4 * 4 + r];

  f32x4 acc[2];
#pragma unroll
  for (int m = 0; m < 2; ++m) acc[m] = f32x4{0.f, 0.f, 0.f, 0.f};

#pragma unroll
  for (int kc = 0; kc < 2; ++kc) {
    const float* yrow = &y[((size_t)(b << 12) + p0 + l4) * 64 + kc * 32 + g4 * 8];
    float4 y0 = *(const float4*)yrow;
    float4 y1 = *(const float4*)(yrow + 4);
    float zv[8] = {y0.x, y0.y, y0.z, y0.w, y1.x, y1.y, y1.z, y1.w};
    bf16x8 zf;
#pragma unroll
    for (int e = 0; e < 8; ++e)
      zf[e] = (short)f2bf(fmaxf(zv[e] * a8[kc][e] + b8[kc][e], 0.f));
#pragma unroll
    for (int m = 0; m < 2; ++m) acc[m] = MFMA16(afw[m][kc], zf, acc[m]);
  }
#pragma unroll
  for (int m = 0; m < 2; ++m)
#pragma unroll
    for (int r = 0; r < 4; ++r)
      out[((size_t)b * 64 + (wid * 2 + m) * 16 + g4 * 4 + r) * (size_t)S_ + p0 + l4] =
          acc[m][r] + fbv[m][r];
}

// --------------------------- host launcher ---------------------------------
extern "C" void kernel_launch(void* const* d_in, const int* in_sizes, int n_in,
                              void* d_out, int out_size, void* d_ws, size_t ws_size,
                              hipStream_t stream) {
  const float* x_s2 = (const float*)d_in[0];
  const float* x_dem = (const float*)d_in[1];
  const float* wq1 = (const float*)d_in[2];
  const float* bq1 = (const float*)d_in[3];
  const float* wk1 = (const float*)d_in[4];
  const float* bk1 = (const float*)d_in[5];
  const float* wv1 = (const float*)d_in[6];
  const float* bv1 = (const float*)d_in[7];
  const float* wq2 = (const float*)d_in[8];
  const float* bq2 = (const float*)d_in[9];
  const float* wk2 = (const float*)d_in[10];
  const float* bk2 = (const float*)d_in[11];
  const float* wv2 = (const float*)d_in[12];
  const float* bv2 = (const float*)d_in[13];
  const float* ln_s2_w = (const float*)d_in[14];
  const float* ln_s2_b = (const float*)d_in[15];
  const float* ln_dem_w = (const float*)d_in[16];
  const float* ln_dem_b = (const float*)d_in[17];
  const float* fw1 = (const float*)d_in[18];
  const float* fb1 = (const float*)d_in[19];
  const float* bn_g = (const float*)d_in[20];
  const float* bn_b = (const float*)d_in[21];
  const float* fw2 = (const float*)d_in[22];
  const float* fb2 = (const float*)d_in[23];

  char* ws = (char*)d_ws;
  unsigned short* xT = (unsigned short*)(ws + OFF_XT);
  unsigned short* wbuf = (unsigned short*)(ws + OFF_WB);
  unsigned short* fw1r = (unsigned short*)(ws + OFF_FW1R);
  unsigned short* Qf = (unsigned short*)(ws + OFF_QT);
  unsigned short* Kf = (unsigned short*)(ws + OFF_KT);
  unsigned short* Vf = (unsigned short*)(ws + OFF_V);
  unsigned short* comb = (unsigned short*)(ws + OFF_COMB);
  float* ybuf = (float*)(ws + OFF_Y);
  float* part = (float*)(ws + OFF_PART);
  float* bnA = (float*)(ws + OFF_BNA);
  float* bnB = (float*)(ws + OFF_BNB);

  k_prep<<<912, 256, 0, stream>>>(wq1, wk1, wv1, wq2, wk2, wv2, fw2, fw1,
                                  x_s2, x_dem, wbuf, fw1r, xT);
  k_proj<<<dim3(64, 4, 2), 256, 0, stream>>>(xT, wbuf, bq1, bk1, bv1,
                                             bq2, bk2, bv2, Qf, Kf, Vf);
  k_attn<<<dim3(8, 64), 256, 0, stream>>>(Qf, Kf, Vf, x_s2, x_dem,
                                          ln_s2_w, ln_s2_b, ln_dem_w, ln_dem_b,
                                          comb);
  k_conv3<<<dim3(256, 4), 128, 0, stream>>>(comb, fw1r, fb1, ybuf, part);
  k_bnfin<<<64, 256, 0, stream>>>(part, bn_g, bn_b, bnA, bnB);
  k_final<<<dim3(256, 4), 128, 0, stream>>>(ybuf, wbuf + 6 * 4096, bnA, bnB, fb2,
                                            (float*)d_out);
}